// Round 9
// baseline (389.946 us; speedup 1.0000x reference)
//
#include <hip/hip_runtime.h>
#include <hip/hip_bf16.h>
#include <stdint.h>

typedef __attribute__((ext_vector_type(8))) short s16x8;    // bf16 MFMA A/B frag (4 VGPRs)
typedef __attribute__((ext_vector_type(4))) float f32x4;    // MFMA C/D frag
typedef __attribute__((ext_vector_type(4))) unsigned short us4;
typedef __attribute__((ext_vector_type(4))) unsigned int u32x4;

// ---- bf16 round-to-nearest-even (inputs are finite normals) ----
__device__ inline unsigned short bf_rne(float f) {
    union { float f; uint32_t u; } v; v.f = f;
    uint32_t u = v.u;
    u += 0x7FFFu + ((u >> 16) & 1u);
    return (unsigned short)(u >> 16);
}

// async global->LDS, 16B per lane; LDS dst is wave-uniform base + lane*16
#define GLD_LDS16(gp, lp)                                                     \
    __builtin_amdgcn_global_load_lds(                                         \
        (const __attribute__((address_space(1))) void*)(gp),                  \
        (__attribute__((address_space(3))) void*)(lp), 16, 0, 0)

// generic (__shared__) pointer -> 32-bit LDS byte offset for ds_read vaddr
#define LDSOFF(p) ((unsigned)(uintptr_t)(__attribute__((address_space(3))) const void*)(p))

// ---------------- Fused prologue (unchanged: at memory roofline) ----------------
__global__ __launch_bounds__(256) void prologue_kernel(
    const float4* __restrict__ x4, us4* __restrict__ xbf4,
    const float4* __restrict__ W4,
    const float4* __restrict__ A4,   // [16][1024] float4
    const float* __restrict__ B,     // [4096][16]
    const float* __restrict__ mag,   // [4096]
    unsigned short* __restrict__ wbf,
    float* __restrict__ scale) {
    const int tid = threadIdx.x;
    if (blockIdx.x < 512) {
        const int m0 = blockIdx.x * 8;
        __shared__ float Bs[8][16];
        __shared__ float red[32];
        if (tid < 128) Bs[tid >> 4][tid & 15] = B[m0 * 16 + tid];
        __syncthreads();
        float ss[8] = {};
        for (int c = tid; c < 1024; c += 256) {
            float4 a[16];
#pragma unroll
            for (int r = 0; r < 16; ++r) a[r] = A4[r * 1024 + c];
#pragma unroll
            for (int i = 0; i < 8; ++i) {
                float4 w = W4[(size_t)(m0 + i) * 1024 + c];
#pragma unroll
                for (int r = 0; r < 16; ++r) {
                    const float br = Bs[i][r];
                    w.x += br * a[r].x; w.y += br * a[r].y;
                    w.z += br * a[r].z; w.w += br * a[r].w;
                }
                ss[i] += w.x * w.x + w.y * w.y + w.z * w.z + w.w * w.w;
                us4 o; o[0] = bf_rne(w.x); o[1] = bf_rne(w.y);
                o[2] = bf_rne(w.z); o[3] = bf_rne(w.w);
                *(us4*)&wbf[(size_t)(m0 + i) * 4096 + c * 4] = o;
            }
        }
        const int lane = tid & 63, wv = tid >> 6;
#pragma unroll
        for (int i = 0; i < 8; ++i) {
            float v = ss[i];
#pragma unroll
            for (int off = 32; off > 0; off >>= 1) v += __shfl_down(v, off, 64);
            if (lane == 0) red[wv * 8 + i] = v;
        }
        __syncthreads();
        if (tid < 8) {
            float tot = red[tid] + red[8 + tid] + red[16 + tid] + red[24 + tid];
            scale[m0 + tid] = mag[m0 + tid] / sqrtf(tot);
        }
    } else {
        const size_t base = (size_t)(blockIdx.x - 512) * 1024 + tid;
#pragma unroll
        for (int j = 0; j < 4; ++j) {
            const size_t idx = base + j * 256;
            float4 a = x4[idx];
            us4 o;
            o[0] = bf_rne(a.x); o[1] = bf_rne(a.y);
            o[2] = bf_rne(a.z); o[3] = bf_rne(a.w);
            xbf4[idx] = o;
        }
    }
}

// ---------------- GEMM: C[8192][4096] = xbf @ wbf^T * scale ----------------
// 256x256 tile, BK=64, 8 waves (2M x 4N), 16x16x32 MFMA.
// (R8, resubmitted after infra failure): (1) B operand loaded DIRECT from
// global (L2-resident panel) into registers via buffer_load_dwordx4 — no LDS
// staging/reads for B. LDS traffic per K-tile drops 256KB->160KB (below the
// MFMA floor). LDS = A only, 64KB.
// (2) ONE barrier per K-tile: only A staging needs cross-wave WAR protection;
// stage(t+1)->buf d^1's previous readers (tile t-1) drained in-wave pre-BAR.
// Waves free-run within a tile -> SIMD's 2 waves drift anti-phase (reads of
// one overlap MFMA of the other); setprio arbitrates.
// vmcnt ledger (per-wave, verified by induction; issue order per tile t:
//   [STAGE_A(t+1) x4] ... [BLD B0(t+1) x4] [BLD B1(t+1) x4]):
//   entry: outstanding = [stage(t) 4 | B0(t) 4 | B1(t) 4] (oldest first)
//   VMW(8) pre-BAR: drains stage(t) -> tile t's A landed in all waves post-BAR
//   VMW(4) mid-tile: drains B0(t),B1(t) (issued ~1 full tile back, L2 covered)
//   exit: [stage(t+1) | B0(t+1) | B1(t+1)]  = entry invariant.
// RAW on A reads: own-wave stage drained by VMW(8) pre-BAR; cross-wave by BAR.
// WAR on staging: buf d^1 readers (t-1) drained via their LGW before BAR.
#define FENCE() asm volatile("" ::: "memory")
#define BAR()   do { FENCE(); __builtin_amdgcn_s_barrier(); FENCE(); } while (0)
#define VMW(n)  asm volatile("s_waitcnt vmcnt(" #n ")" ::: "memory")
#define LGW(n)  asm volatile("s_waitcnt lgkmcnt(" #n ")" ::: "memory")
#define SB0()   __builtin_amdgcn_sched_barrier(0)
#define PRIO1() __builtin_amdgcn_s_setprio(1)
#define PRIO0() __builtin_amdgcn_s_setprio(0)

// precomputed-address LDS read: vaddr VGPR + literal offset immediate
#define DSR(dst, va, IMM) \
    asm volatile("ds_read_b128 %0, %1 offset:" #IMM : "=v"(dst) : "v"(va))

// B fragment load: SRSRC buffer_load, 32-bit voffset (wave-private, no barrier)
#define BLD(dst, voff) \
    asm volatile("buffer_load_dwordx4 %0, %1, %2, 0 offen" \
                 : "=v"(dst) : "v"(voff), "s"(srd))

__global__ __launch_bounds__(512, 2) void dora_gemm(
    const unsigned short* __restrict__ xbf,   // [8192][4096] bf16
    const unsigned short* __restrict__ wbf,   // [4096][4096] bf16
    const float* __restrict__ scale,          // [4096]
    float* __restrict__ out) {                // [8192][4096] fp32
    __shared__ __align__(16) unsigned short As[2][256 * 64];   // 64 KB total

    const int tid  = threadIdx.x;
    const int lane = tid & 63;
    const int w    = tid >> 6;     // wave 0..7
    const int wm   = w >> 2;       // 0..1
    const int wn   = w & 3;        // 0..3
    const int q    = lane >> 4;
    const int c15  = lane & 15;

    // XCD mapping: 8 XCDs x 64 blocks; each XCD owns an 8M x 8N tile square
    // (bijective over the 32x16 grid); M sweeps fastest within the square.
    const int bid = blockIdx.x;
    const int xcd = bid & 7, sub = bid >> 3;
    const int tileM = (((xcd & 3) << 3) | (sub & 7)) << 8;   // 0..31 * 256
    const int tileN = (((xcd >> 2) << 3) | (sub >> 3)) << 8; // 0..15 * 256

    // A staging: thread t, load j covers linear chunk c = j*512 + t of a
    // half-tile (128 rows x 64 bf16). row = c>>3, phys chunk = c&7; XOR
    // swizzle via pre-swizzled global source (phys p holds logical p^(r&7)).
    const int r0 = tid >> 3;              // 0..63
    const int lc = (tid & 7) ^ (r0 & 7);
    const size_t aoff = (size_t)(tileM + r0) * 4096 + lc * 8;
    const int ld0 = (w * 64) * 8;         // shorts; wave-uniform LDS base, j=0
    const int ld1 = (512 + w * 64) * 8;   // j=1 (+64 rows)

#define STAGE_A(d, h, k0) do {                                                            \
    GLD_LDS16(xbf + aoff + (size_t)((h) * 128) * 4096 + (k0),      &As[d][(h) * 8192 + ld0]); \
    GLD_LDS16(xbf + aoff + (size_t)((h) * 128 + 64) * 4096 + (k0), &As[d][(h) * 8192 + ld1]); \
} while (0)

    // Precomputed A ds_read addresses (buf0, mh0). phys = (kc*4+q)^(c15&7).
    const int rb = c15 & 7;
    unsigned aA[4][2];
#pragma unroll
    for (int mt = 0; mt < 4; ++mt)
#pragma unroll
        for (int kc = 0; kc < 2; ++kc)
            aA[mt][kc] = LDSOFF(&As[0][(wm * 64 + mt * 16 + c15) * 64 +
                                       ((kc * 4 + q) ^ rb) * 8]);

    // B SRSRC + per-lane voffsets. Lane (q,c15) of frag [nh][nt][kc] holds
    // wbf row (tileN + nh*128 + wn*32 + nt*16 + c15), k-bytes (kc*4+q)*16
    // (+ t*128 per K-tile). Same data as the old LDS path (verified).
    const unsigned long long wb = (unsigned long long)(uintptr_t)wbf;
    const u32x4 srd = { (unsigned)wb, (unsigned)(wb >> 32),
                        0xFFFFFFFFu, 0x00020000u };
    unsigned v000 = (unsigned)((tileN + wn * 32 + c15) * 8192 + q * 16);
    unsigned v001 = v000 + 64;            // kc=1
    unsigned v010 = v000 + 16 * 8192;     // nt=1
    unsigned v011 = v010 + 64;
    unsigned v100 = v000 + 128 * 8192;    // nh=1
    unsigned v101 = v100 + 64;
    unsigned v110 = v100 + 16 * 8192;
    unsigned v111 = v110 + 64;

    s16x8 af[4][2];      // A frags [mt][kc], current mh
    s16x8 bfx[2][2][2];  // B frags [nh][nt][kc], resident per K-tile
    f32x4 acc[8][4] = {};

#define BLD_B0() do { BLD(bfx[0][0][0], v000); BLD(bfx[0][0][1], v001);       \
                      BLD(bfx[0][1][0], v010); BLD(bfx[0][1][1], v011); } while (0)
#define BLD_B1() do { BLD(bfx[1][0][0], v100); BLD(bfx[1][0][1], v101);       \
                      BLD(bfx[1][1][0], v110); BLD(bfx[1][1][1], v111); } while (0)
#define VBUMP() do { v000 += 128; v001 += 128; v010 += 128; v011 += 128;      \
                     v100 += 128; v101 += 128; v110 += 128; v111 += 128; } while (0)

    // A reads: kc0 group first, then kc1 (LGW(4) covers first cluster)
#define RD_A0(IMM) do {                                                       \
    DSR(af[0][0], aA[0][0], IMM); DSR(af[1][0], aA[1][0], IMM);               \
    DSR(af[2][0], aA[2][0], IMM); DSR(af[3][0], aA[3][0], IMM);               \
    DSR(af[0][1], aA[0][1], IMM); DSR(af[1][1], aA[1][1], IMM);               \
    DSR(af[2][1], aA[2][1], IMM); DSR(af[3][1], aA[3][1], IMM); } while (0)
#define RD_A1(IMM) RD_A0(IMM)

#define MFMA_H(mh, nh, kcv) do {                                              \
    _Pragma("unroll") for (int mt = 0; mt < 4; ++mt)                          \
    _Pragma("unroll") for (int nt = 0; nt < 2; ++nt)                          \
        acc[(mh) * 4 + mt][(nh) * 2 + nt] =                                   \
            __builtin_amdgcn_mfma_f32_16x16x32_bf16(                          \
                af[mt][kcv], bfx[nh][nt][kcv],                                \
                acc[(mh) * 4 + mt][(nh) * 2 + nt], 0, 0, 0);                  \
} while (0)

    // Tile body. Quadrant order Q00,Q01,Q10,Q11 (B0 freed before B1 so BLDs
    // for t+1 slot in earliest-legal positions). Per-cell kc order unchanged.
#define TILEB(I0, I1, DD, KN) do {                                            \
    VMW(8); BAR();                                                            \
    STAGE_A(DD, 0, KN); STAGE_A(DD, 1, KN);                                   \
    RD_A0(I0);                                                                \
    VMW(4);                                                                   \
    LGW(4); SB0(); PRIO1(); MFMA_H(0, 0, 0); PRIO0();                         \
    LGW(0); SB0(); PRIO1(); MFMA_H(0, 0, 1); MFMA_H(0, 1, 0);                 \
                           MFMA_H(0, 1, 1); PRIO0();                          \
    RD_A1(I1);                                                                \
    LGW(4); SB0(); PRIO1(); MFMA_H(1, 0, 0); PRIO0();                         \
    LGW(0); SB0(); PRIO1(); MFMA_H(1, 0, 1); PRIO0();                         \
    BLD_B0();                                                                 \
    PRIO1(); MFMA_H(1, 1, 0); MFMA_H(1, 1, 1); PRIO0();                       \
    BLD_B1(); VBUMP();                                                        \
} while (0)

    // prologue: stage tile0 A -> buf0; load B(0); establishes entry invariant.
    STAGE_A(0, 0, 0); STAGE_A(0, 1, 0);
    BLD_B0(); BLD_B1(); VBUMP();

    // tiles 0..61 (pairs); tile 2i stages 2i+1 -> buf1, loads B(2i+1);
    // tile 2i+1 stages 2i+2 -> buf0, loads B(2i+2).
    for (int kn = 64; kn <= 3904; kn += 128) {
        TILEB(0, 16384, 1, kn);            // even tile (buf0)
        TILEB(32768, 49152, 0, kn + 64);   // odd tile  (buf1)
    }
    // tile 62 (buf0): stages tile 63, loads B(63)
    TILEB(0, 16384, 1, 4032);
    // tile 63 (buf1): no stage, no BLD
    VMW(8); BAR();
    RD_A0(32768);
    VMW(0);
    LGW(4); SB0(); PRIO1(); MFMA_H(0, 0, 0); PRIO0();
    LGW(0); SB0(); PRIO1(); MFMA_H(0, 0, 1); MFMA_H(0, 1, 0); MFMA_H(0, 1, 1); PRIO0();
    RD_A1(49152);
    LGW(4); SB0(); PRIO1(); MFMA_H(1, 0, 0); PRIO0();
    LGW(0); SB0(); PRIO1(); MFMA_H(1, 0, 1); MFMA_H(1, 1, 0); MFMA_H(1, 1, 1); PRIO0();

    // epilogue: C/D layout col=lane&15, row=(lane>>4)*4+reg ; scale by mag/norm
#pragma unroll
    for (int nh = 0; nh < 2; ++nh)
#pragma unroll
    for (int nt = 0; nt < 2; ++nt) {
        const int col = tileN + nh * 128 + wn * 32 + nt * 16 + c15;
        const float s = scale[col];
#pragma unroll
        for (int mh = 0; mh < 2; ++mh)
#pragma unroll
        for (int mt = 0; mt < 4; ++mt) {
            const int row0 = tileM + mh * 128 + wm * 64 + mt * 16 + q * 4;
#pragma unroll
            for (int r = 0; r < 4; ++r)
                out[(size_t)(row0 + r) * 4096 + col] = acc[mh * 4 + mt][nh * 2 + nt][r] * s;
        }
    }
}

extern "C" void kernel_launch(void* const* d_in, const int* in_sizes, int n_in,
                              void* d_out, int out_size, void* d_ws, size_t ws_size,
                              hipStream_t stream) {
    const float* x   = (const float*)d_in[0];   // [4,2048,4096]
    const float* W   = (const float*)d_in[1];   // [4096,4096]
    const float* A   = (const float*)d_in[2];   // [16,4096]
    const float* B   = (const float*)d_in[3];   // [4096,16]
    const float* mag = (const float*)d_in[4];   // [4096]
    float* out = (float*)d_out;

    const size_t XBF_BYTES = (size_t)8192 * 4096 * 2;  // 67,108,864
    const size_t WBF_BYTES = (size_t)4096 * 4096 * 2;  // 33,554,432
    const size_t NEEDED = XBF_BYTES + WBF_BYTES + 4096 * sizeof(float);
    if (ws_size < NEEDED) return;

    unsigned short* xbf = (unsigned short*)d_ws;
    unsigned short* wbf = (unsigned short*)((char*)d_ws + XBF_BYTES);
    float* scale = (float*)((char*)d_ws + XBF_BYTES + WBF_BYTES);

    prologue_kernel<<<8704, 256, 0, stream>>>((const float4*)x, (us4*)xbf,
                                              (const float4*)W, (const float4*)A,
                                              B, mag, wbf, scale);
    dora_gemm<<<2048 / 4, 512, 0, stream>>>(xbf, wbf, scale, out);
}

// Round 10
// 313.851 us; speedup vs baseline: 1.2425x; 1.2425x over previous
//
#include <hip/hip_runtime.h>
#include <hip/hip_bf16.h>
#include <stdint.h>

typedef __attribute__((ext_vector_type(8))) short s16x8;    // bf16 MFMA A/B frag (4 VGPRs)
typedef __attribute__((ext_vector_type(4))) float f32x4;    // MFMA C/D frag
typedef __attribute__((ext_vector_type(4))) unsigned short us4;

// ---- bf16 round-to-nearest-even (inputs are finite normals) ----
__device__ inline unsigned short bf_rne(float f) {
    union { float f; uint32_t u; } v; v.f = f;
    uint32_t u = v.u;
    u += 0x7FFFu + ((u >> 16) & 1u);
    return (unsigned short)(u >> 16);
}

// async global->LDS, 16B per lane; LDS dst is wave-uniform base + lane*16
#define GLD_LDS16(gp, lp)                                                     \
    __builtin_amdgcn_global_load_lds(                                         \
        (const __attribute__((address_space(1))) void*)(gp),                  \
        (__attribute__((address_space(3))) void*)(lp), 16, 0, 0)

// generic (__shared__) pointer -> 32-bit LDS byte offset for ds_read vaddr
#define LDSOFF(p) ((unsigned)(uintptr_t)(__attribute__((address_space(3))) const void*)(p))

// ---------------- Fused prologue (unchanged: at memory roofline) ----------------
__global__ __launch_bounds__(256) void prologue_kernel(
    const float4* __restrict__ x4, us4* __restrict__ xbf4,
    const float4* __restrict__ W4,
    const float4* __restrict__ A4,   // [16][1024] float4
    const float* __restrict__ B,     // [4096][16]
    const float* __restrict__ mag,   // [4096]
    unsigned short* __restrict__ wbf,
    float* __restrict__ scale) {
    const int tid = threadIdx.x;
    if (blockIdx.x < 512) {
        const int m0 = blockIdx.x * 8;
        __shared__ float Bs[8][16];
        __shared__ float red[32];
        if (tid < 128) Bs[tid >> 4][tid & 15] = B[m0 * 16 + tid];
        __syncthreads();
        float ss[8] = {};
        for (int c = tid; c < 1024; c += 256) {
            float4 a[16];
#pragma unroll
            for (int r = 0; r < 16; ++r) a[r] = A4[r * 1024 + c];
#pragma unroll
            for (int i = 0; i < 8; ++i) {
                float4 w = W4[(size_t)(m0 + i) * 1024 + c];
#pragma unroll
                for (int r = 0; r < 16; ++r) {
                    const float br = Bs[i][r];
                    w.x += br * a[r].x; w.y += br * a[r].y;
                    w.z += br * a[r].z; w.w += br * a[r].w;
                }
                ss[i] += w.x * w.x + w.y * w.y + w.z * w.z + w.w * w.w;
                us4 o; o[0] = bf_rne(w.x); o[1] = bf_rne(w.y);
                o[2] = bf_rne(w.z); o[3] = bf_rne(w.w);
                *(us4*)&wbf[(size_t)(m0 + i) * 4096 + c * 4] = o;
            }
        }
        const int lane = tid & 63, wv = tid >> 6;
#pragma unroll
        for (int i = 0; i < 8; ++i) {
            float v = ss[i];
#pragma unroll
            for (int off = 32; off > 0; off >>= 1) v += __shfl_down(v, off, 64);
            if (lane == 0) red[wv * 8 + i] = v;
        }
        __syncthreads();
        if (tid < 8) {
            float tot = red[tid] + red[8 + tid] + red[16 + tid] + red[24 + tid];
            scale[m0 + tid] = mag[m0 + tid] / sqrtf(tot);
        }
    } else {
        const size_t base = (size_t)(blockIdx.x - 512) * 1024 + tid;
#pragma unroll
        for (int j = 0; j < 4; ++j) {
            const size_t idx = base + j * 256;
            float4 a = x4[idx];
            us4 o;
            o[0] = bf_rne(a.x); o[1] = bf_rne(a.y);
            o[2] = bf_rne(a.z); o[3] = bf_rne(a.w);
            xbf4[idx] = o;
        }
    }
}

// ---------------- GEMM: C[8192][4096] = xbf @ wbf^T * scale ----------------
// 256x256 tile, BK=64, 8 waves (2M x 4N), 16x16x32 MFMA, R5's exact datapath
// (A+B LDS-staged, XOR swizzle, precomputed inline-asm ds_read, 0 conflicts).
// NEW (R10): ONE barrier per K-tile (unconfounded test of the lockstep
// hypothesis; R8 bundled it with the losing B-gather). Per tile t (buf d=t&1):
//   VMW(0)            — drains stage(t), issued a full tile (~2000cy) ago
//   BAR               — all waves' stage(t) landed; all t-1 reads drained
//   stage(t+1)->d^1   — WAR-safe: d^1's readers were tile t-1, drained pre-BAR
//   24 ds_read + 64 MFMA, counted lgkmcnt, NO barriers — waves free-run,
//   SIMD-mates drift anti-phase (one's reads under the other's MFMAs).
// RAW in-tile: own-wave reads ordered by lgkmcnt; cross-wave by VMW(0)+BAR.
#define FENCE() asm volatile("" ::: "memory")
#define BAR()   do { FENCE(); __builtin_amdgcn_s_barrier(); FENCE(); } while (0)
#define VMW(n)  asm volatile("s_waitcnt vmcnt(" #n ")" ::: "memory")
#define LGW(n)  asm volatile("s_waitcnt lgkmcnt(" #n ")" ::: "memory")
#define SB0()   __builtin_amdgcn_sched_barrier(0)
#define PRIO1() __builtin_amdgcn_s_setprio(1)
#define PRIO0() __builtin_amdgcn_s_setprio(0)

// precomputed-address LDS read: vaddr VGPR + literal offset immediate
#define DSR(dst, va, IMM) \
    asm volatile("ds_read_b128 %0, %1 offset:" #IMM : "=v"(dst) : "v"(va))

__global__ __launch_bounds__(512, 2) void dora_gemm(
    const unsigned short* __restrict__ xbf,   // [8192][4096] bf16
    const unsigned short* __restrict__ wbf,   // [4096][4096] bf16
    const float* __restrict__ scale,          // [4096]
    float* __restrict__ out) {                // [8192][4096] fp32
    __shared__ __align__(16) unsigned short As[2][256 * 64];
    __shared__ __align__(16) unsigned short Bs[2][256 * 64];

    const int tid  = threadIdx.x;
    const int lane = tid & 63;
    const int w    = tid >> 6;     // wave 0..7
    const int wm   = w >> 2;       // 0..1
    const int wn   = w & 3;        // 0..3
    const int q    = lane >> 4;
    const int c15  = lane & 15;

    // XCD mapping: 8 XCDs x 64 blocks; each XCD owns an 8M x 8N tile square
    // (bijective over the 32x16 grid); M sweeps fastest within the square.
    const int bid = blockIdx.x;
    const int xcd = bid & 7, sub = bid >> 3;
    const int tileM = (((xcd & 3) << 3) | (sub & 7)) << 8;   // 0..31 * 256
    const int tileN = (((xcd >> 2) << 3) | (sub >> 3)) << 8; // 0..15 * 256

    // staging: thread t, load j covers linear chunk c = j*512 + t of a half-tile
    // (128 rows x 64 bf16). row-in-half = c>>3, phys 16B chunk = c&7; XOR swizzle:
    // phys chunk p of row r holds logical chunk p ^ (r&7) -> pre-swizzled source.
    const int r0 = tid >> 3;              // 0..63
    const int lc = (tid & 7) ^ (r0 & 7);
    const size_t aoff = (size_t)(tileM + r0) * 4096 + lc * 8;
    const size_t boff = (size_t)(tileN + r0) * 4096 + lc * 8;
    const int ld0 = (w * 64) * 8;         // shorts; wave-uniform LDS base, j=0
    const int ld1 = (512 + w * 64) * 8;   // j=1 (+64 rows)

#define STAGE_A(d, h, k0) do {                                                            \
    GLD_LDS16(xbf + aoff + (size_t)((h) * 128) * 4096 + (k0),      &As[d][(h) * 8192 + ld0]); \
    GLD_LDS16(xbf + aoff + (size_t)((h) * 128 + 64) * 4096 + (k0), &As[d][(h) * 8192 + ld1]); \
} while (0)
#define STAGE_B(d, h, k0) do {                                                            \
    GLD_LDS16(wbf + boff + (size_t)((h) * 128) * 4096 + (k0),      &Bs[d][(h) * 8192 + ld0]); \
    GLD_LDS16(wbf + boff + (size_t)((h) * 128 + 64) * 4096 + (k0), &Bs[d][(h) * 8192 + ld1]); \
} while (0)

    // Precomputed ds_read base addresses (buf0, mh0/nh0). For every frag,
    // row&7 == c15&7, so phys = (kc*4+q)^(c15&7) is row-independent.
    const int rb = c15 & 7;
    unsigned aA[4][2], aB[2][2];
#pragma unroll
    for (int mt = 0; mt < 4; ++mt)
#pragma unroll
        for (int kc = 0; kc < 2; ++kc)
            aA[mt][kc] = LDSOFF(&As[0][(wm * 64 + mt * 16 + c15) * 64 +
                                       ((kc * 4 + q) ^ rb) * 8]);
#pragma unroll
    for (int nt = 0; nt < 2; ++nt)
#pragma unroll
        for (int kc = 0; kc < 2; ++kc)
            aB[nt][kc] = LDSOFF(&Bs[0][(wn * 32 + nt * 16 + c15) * 64 +
                                       ((kc * 4 + q) ^ rb) * 8]);

    s16x8 af[4][2];      // A frags [mt][kc], current mh (held across 2 quadrants)
    s16x8 bfx[2][2][2];  // B frags [nh][nt][kc], fully resident per K-tile
    f32x4 acc[8][4] = {};

    // IMM encodes (buffer, half): buf = +32768, mh/nh = +16384
#define RD_A(IMM) do {                                                        \
    DSR(af[0][0], aA[0][0], IMM); DSR(af[0][1], aA[0][1], IMM);               \
    DSR(af[1][0], aA[1][0], IMM); DSR(af[1][1], aA[1][1], IMM);               \
    DSR(af[2][0], aA[2][0], IMM); DSR(af[2][1], aA[2][1], IMM);               \
    DSR(af[3][0], aA[3][0], IMM); DSR(af[3][1], aA[3][1], IMM); } while (0)
#define RD_B(nh, IMM) do {                                                    \
    DSR(bfx[nh][0][0], aB[0][0], IMM); DSR(bfx[nh][0][1], aB[0][1], IMM);     \
    DSR(bfx[nh][1][0], aB[1][0], IMM); DSR(bfx[nh][1][1], aB[1][1], IMM); } while (0)

#define MFMA_Q(mh, nh) do {                                                   \
    _Pragma("unroll") for (int mt = 0; mt < 4; ++mt)                          \
    _Pragma("unroll") for (int nt = 0; nt < 2; ++nt)                          \
    _Pragma("unroll") for (int kc = 0; kc < 2; ++kc)                          \
        acc[(mh) * 4 + mt][(nh) * 2 + nt] =                                   \
            __builtin_amdgcn_mfma_f32_16x16x32_bf16(                          \
                af[mt][kc], bfx[nh][nt][kc],                                  \
                acc[(mh) * 4 + mt][(nh) * 2 + nt], 0, 0, 0);                  \
} while (0)

    // One-barrier K-tile body. Read issue order: [B0(4), A0(8)] [B1(4)] so
    // LGW(4) covers Q00's 12 operands while B1 drains under Q00's MFMAs.
    // Quadrants: Q00, Q01 (A held), Q11 (B1 held, A1 fresh), Q10 (resident).
#define TILE1(IA0, IA1, IB0, IB1, DD, KN) do {                                \
    VMW(0); BAR();                                                            \
    STAGE_A(DD, 0, KN); STAGE_B(DD, 0, KN);                                   \
    STAGE_B(DD, 1, KN); STAGE_A(DD, 1, KN);                                   \
    RD_B(0, IB0); RD_A(IA0);                                                  \
    RD_B(1, IB1);                                                             \
    LGW(4); SB0(); PRIO1(); MFMA_Q(0, 0); PRIO0();                            \
    LGW(0); SB0(); PRIO1(); MFMA_Q(0, 1); PRIO0();                            \
    RD_A(IA1);                                                                \
    LGW(0); SB0(); PRIO1(); MFMA_Q(1, 1); PRIO0();                            \
    PRIO1(); MFMA_Q(1, 0); PRIO0();                                           \
} while (0)

    // prologue: stage tile0 -> buf0 (8 loads); loop entry VMW(0)+BAR drains it.
    STAGE_A(0, 0, 0); STAGE_B(0, 0, 0); STAGE_B(0, 1, 0); STAGE_A(0, 1, 0);

    // pairs (t=2i, 2i+1), i=0..30: even (buf0) stages kn=(2i+1)*64 -> buf1;
    // odd (buf1) stages kn+64 -> buf0.
    for (int kn = 64; kn <= 3904; kn += 128) {
        TILE1(0, 16384, 0, 16384, 1, kn);              // even tile, buf0
        TILE1(32768, 49152, 32768, 49152, 0, kn + 64); // odd tile,  buf1
    }
    // tile 62 (buf0): stages tile 63 -> buf1
    TILE1(0, 16384, 0, 16384, 1, 4032);
    // tile 63 (buf1): no staging
    VMW(0); BAR();
    RD_B(0, 32768); RD_A(32768);
    RD_B(1, 49152);
    LGW(4); SB0(); PRIO1(); MFMA_Q(0, 0); PRIO0();
    LGW(0); SB0(); PRIO1(); MFMA_Q(0, 1); PRIO0();
    RD_A(49152);
    LGW(0); SB0(); PRIO1(); MFMA_Q(1, 1); MFMA_Q(1, 0); PRIO0();

    // epilogue: C/D layout col=lane&15, row=(lane>>4)*4+reg ; scale by mag/norm
#pragma unroll
    for (int nh = 0; nh < 2; ++nh)
#pragma unroll
    for (int nt = 0; nt < 2; ++nt) {
        const int col = tileN + nh * 128 + wn * 32 + nt * 16 + c15;
        const float s = scale[col];
#pragma unroll
        for (int mh = 0; mh < 2; ++mh)
#pragma unroll
        for (int mt = 0; mt < 4; ++mt) {
            const int row0 = tileM + mh * 128 + wm * 64 + mt * 16 + q * 4;
#pragma unroll
            for (int r = 0; r < 4; ++r)
                out[(size_t)(row0 + r) * 4096 + col] = acc[mh * 4 + mt][nh * 2 + nt][r] * s;
        }
    }
}

extern "C" void kernel_launch(void* const* d_in, const int* in_sizes, int n_in,
                              void* d_out, int out_size, void* d_ws, size_t ws_size,
                              hipStream_t stream) {
    const float* x   = (const float*)d_in[0];   // [4,2048,4096]
    const float* W   = (const float*)d_in[1];   // [4096,4096]
    const float* A   = (const float*)d_in[2];   // [16,4096]
    const float* B   = (const float*)d_in[3];   // [4096,16]
    const float* mag = (const float*)d_in[4];   // [4096]
    float* out = (float*)d_out;

    const size_t XBF_BYTES = (size_t)8192 * 4096 * 2;  // 67,108,864
    const size_t WBF_BYTES = (size_t)4096 * 4096 * 2;  // 33,554,432
    const size_t NEEDED = XBF_BYTES + WBF_BYTES + 4096 * sizeof(float);
    if (ws_size < NEEDED) return;

    unsigned short* xbf = (unsigned short*)d_ws;
    unsigned short* wbf = (unsigned short*)((char*)d_ws + XBF_BYTES);
    float* scale = (float*)((char*)d_ws + XBF_BYTES + WBF_BYTES);

    prologue_kernel<<<8704, 256, 0, stream>>>((const float4*)x, (us4*)xbf,
                                              (const float4*)W, (const float4*)A,
                                              B, mag, wbf, scale);
    dora_gemm<<<512, 512, 0, stream>>>(xbf, wbf, scale, out);
}